// Round 1
// baseline (511.663 us; speedup 1.0000x reference)
//
#include <hip/hip_runtime.h>
#include <hip/hip_bf16.h>

// out[b,t,o] = bias[o] + sum_{c<7,m<8,h<3} W[o, c*8+m, h] * Z[b, c*8+m, (t+h-1)&2047]
// Z[b, c*8+m, s] = (s >= 168) ? x[b, s-24m, c] : 0
// GEMM: M = 32*2048, N = 512, K = 168 (padded to 192), bf16 MFMA, fp32 accum.

#define TAO   24
#define MTAPS 7
#define C_IN  7
#define SEQ   2048
#define DMODEL 512
#define KDIM  168   // 56*3
#define KPAD  192   // 6*32
#define LDK   200   // LDS row stride in bf16 elems (400 B -> 2-way bank alias, free)
#define BM    128
#define BN    128

typedef __attribute__((ext_vector_type(8))) short frag_ab;  // 8 bf16
typedef __attribute__((ext_vector_type(4))) float frag_cd;  // 4 fp32

__global__ __launch_bounds__(256, 1)
void fused_tokenconv_kernel(const float* __restrict__ x,
                            const float* __restrict__ W,
                            const float* __restrict__ bias,
                            float* __restrict__ out)
{
    __shared__ __hip_bfloat16 As[BM][LDK];  // V tile  [t_local][k]
    __shared__ __hip_bfloat16 Bs[BN][LDK];  // W tile  [o_local][k]

    const int tid = threadIdx.x;
    const int blk = blockIdx.x;
    const int nb  = blk & 3;        // 4 N-blocks (512/128)
    const int mb  = blk >> 2;       // 512 M-blocks
    const int b   = mb >> 4;        // 16 t-blocks per batch
    const int t0  = (mb & 15) * BM;
    const int o0  = nb * BN;

    const float* xb = x + b * (SEQ * C_IN);

    // ---- stage W tile: Bs[o_l][i] = W[(o0+o_l)*168 + i], zero-pad i in [168,192)
    for (int idx = tid; idx < BN * KPAD; idx += 256) {
        int o_l = idx / KPAD;
        int i   = idx - o_l * KPAD;
        float v = (i < KDIM) ? W[(o0 + o_l) * KDIM + i] : 0.0f;
        Bs[o_l][i] = __float2bfloat16(v);
    }

    // ---- stage V tile: As[t_l][i], i = (c*8+m)*3+h = c*24 + m*3 + h
    for (int idx = tid; idx < BM * KPAD; idx += 256) {
        int t_l = idx / KPAD;
        int i   = idx - t_l * KPAD;
        float v = 0.0f;
        if (i < KDIM) {
            int c = i / 24;
            int r = i - c * 24;
            int m = r / 3;
            int h = r - m * 3;
            int s = (t0 + t_l + h - 1 + SEQ) & (SEQ - 1);   // wrap pad
            if (s >= MTAPS * TAO) {
                v = xb[(s - TAO * m) * C_IN + c];
            }
        }
        As[t_l][i] = __float2bfloat16(v);
    }
    __syncthreads();

    // ---- MFMA: 4 waves in 2x2, each wave 64x64 = 4x4 tiles of 16x16
    const int wave = tid >> 6;
    const int lane = tid & 63;
    const int wm   = (wave >> 1) * 64;
    const int wn   = (wave & 1) * 64;
    const int l15  = lane & 15;
    const int quad = lane >> 4;

    frag_cd acc[4][4];
#pragma unroll
    for (int i = 0; i < 4; i++)
#pragma unroll
        for (int j = 0; j < 4; j++)
            acc[i][j] = (frag_cd){0.f, 0.f, 0.f, 0.f};

#pragma unroll
    for (int kc = 0; kc < KPAD / 32; kc++) {
        const int kof = kc * 32 + quad * 8;
        frag_ab a[4], bf[4];
#pragma unroll
        for (int mi = 0; mi < 4; mi++)
            a[mi] = *(const frag_ab*)&As[wm + mi * 16 + l15][kof];
#pragma unroll
        for (int ni = 0; ni < 4; ni++)
            bf[ni] = *(const frag_ab*)&Bs[wn + ni * 16 + l15][kof];
#pragma unroll
        for (int mi = 0; mi < 4; mi++)
#pragma unroll
            for (int ni = 0; ni < 4; ni++)
                acc[mi][ni] = __builtin_amdgcn_mfma_f32_16x16x32_bf16(
                    a[mi], bf[ni], acc[mi][ni], 0, 0, 0);
    }

    // ---- epilogue: C/D layout col = lane&15 (n), row = quad*4 + reg (m)
    float* outb = out + (size_t)b * SEQ * DMODEL;
#pragma unroll
    for (int ni = 0; ni < 4; ni++) {
        const int o  = o0 + wn + ni * 16 + l15;
        const float bv = bias[o];
#pragma unroll
        for (int mi = 0; mi < 4; mi++) {
#pragma unroll
            for (int reg = 0; reg < 4; reg++) {
                const int t = t0 + wm + mi * 16 + quad * 4 + reg;
                outb[(size_t)t * DMODEL + o] = acc[mi][ni][reg] + bv;
            }
        }
    }
}

extern "C" void kernel_launch(void* const* d_in, const int* in_sizes, int n_in,
                              void* d_out, int out_size, void* d_ws, size_t ws_size,
                              hipStream_t stream) {
    const float* x    = (const float*)d_in[0];   // (32, 2048, 7) fp32
    const float* W    = (const float*)d_in[1];   // (512, 56, 3) fp32
    const float* bias = (const float*)d_in[2];   // (512,) fp32
    float* out        = (float*)d_out;           // (32, 2048, 512) fp32

    const int B = in_sizes[0] / (SEQ * C_IN);    // 32
    dim3 grid(B * (SEQ / BM) * (DMODEL / BN));   // 2048
    dim3 block(256);
    hipLaunchKernelGGL(fused_tokenconv_kernel, grid, block, 0, stream,
                       x, W, bias, out);
}

// Round 2
// 186.250 us; speedup vs baseline: 2.7472x; 2.7472x over previous
//
#include <hip/hip_runtime.h>
#include <hip/hip_bf16.h>
#include <stdint.h>

// out[b,t,o] = bias[o] + sum_{c<7,m<8,h<3} W[o, c*8+m, h] * Z[b, c*8+m, (t+h-1)&2047]
// Z[b, cm, s] = (s >= 168) ? x[b, s-24m, c] : 0
// Two-phase: (1) materialize V (65536 x 200 bf16, k-padded) + Wbf (512 x 200 bf16)
// into d_ws; (2) m97-style GEMM with global_load_lds staging.

#define TAO    24
#define MTAPS  7
#define C_IN   7
#define SEQ    2048
#define DMODEL 512
#define KDIM   168   // 56*3
#define KPAD   192   // 6*32 (MFMA range)
#define LDK    200   // stored row stride in bf16 (400 B = 25*16 B; 2-way LDS alias only)
#define NROWS  65536 // 32*2048
#define BM     128
#define BN     64

typedef __attribute__((ext_vector_type(8))) short frag_ab;  // 8 bf16
typedef __attribute__((ext_vector_type(4))) float frag_cd;  // 4 fp32

// ---------------- phase 1a: build V ----------------
// task = row*25 + k8 ; writes V[row][8*k8 .. 8*k8+7] as one 16 B store
__global__ __launch_bounds__(256)
void build_v_kernel(const float* __restrict__ x, __hip_bfloat16* __restrict__ V)
{
    const int task = blockIdx.x * 256 + threadIdx.x;   // 65536*25 tasks
    const int row  = task / 25;
    const int k8   = task - row * 25;
    const int b    = row >> 11;
    const int t    = row & (SEQ - 1);
    const float* xb = x + b * (SEQ * C_IN);

    union { short s[8]; int4 v; } u;
#pragma unroll
    for (int j = 0; j < 8; j++) {
        const int k = k8 * 8 + j;
        float v = 0.0f;
        if (k < KDIM) {
            const int c = k / 24;
            const int r = k - c * 24;
            const int m = r / 3;
            const int h = r - m * 3;
            const int s = (t + h - 1 + SEQ) & (SEQ - 1);
            if (s >= MTAPS * TAO) v = xb[(s - TAO * m) * C_IN + c];
        }
        __hip_bfloat16 bv = __float2bfloat16(v);
        u.s[j] = *reinterpret_cast<short*>(&bv);
    }
    reinterpret_cast<int4*>(V)[task] = u.v;
}

// ---------------- phase 1b: convert W ----------------
__global__ __launch_bounds__(256)
void build_w_kernel(const float* __restrict__ W, __hip_bfloat16* __restrict__ Wb)
{
    const int task = blockIdx.x * 256 + threadIdx.x;   // 512*25 tasks
    const int o  = task / 25;
    const int k8 = task - o * 25;

    union { short s[8]; int4 v; } u;
#pragma unroll
    for (int j = 0; j < 8; j++) {
        const int k = k8 * 8 + j;
        float v = (k < KDIM) ? W[o * KDIM + k] : 0.0f;
        __hip_bfloat16 bv = __float2bfloat16(v);
        u.s[j] = *reinterpret_cast<short*>(&bv);
    }
    reinterpret_cast<int4*>(Wb)[task] = u.v;
}

// ---------------- phase 2: GEMM ----------------
__global__ __launch_bounds__(256, 2)
void gemm_kernel(const __hip_bfloat16* __restrict__ V,
                 const __hip_bfloat16* __restrict__ Wb,
                 const float* __restrict__ bias,
                 float* __restrict__ out)
{
    __shared__ __hip_bfloat16 lds[BM * LDK + BN * LDK];  // 51200 + 25600 B = 76.8 KB
    __hip_bfloat16* As = lds;
    __hip_bfloat16* Bs = lds + BM * LDK;

    const int tid = threadIdx.x;
    const int nb  = blockIdx.x & 7;      // 8 N-blocks
    const int mb  = blockIdx.x >> 3;     // 512 M-blocks
    const int o0  = nb * BN;

    // --- stage A: 51200 B flat contiguous (V rows are stride-400B, matches LDS)
    {
        const char* src = (const char*)(V + (size_t)mb * BM * LDK);
        char* dst = (char*)As;
#pragma unroll
        for (int it = 0; it < 12; it++) {
            const int off = (it * 256 + tid) * 16;
            __builtin_amdgcn_global_load_lds(
                (const __attribute__((address_space(1))) uint32_t*)(src + off),
                (__attribute__((address_space(3))) uint32_t*)(dst + off), 16, 0, 0);
        }
        if (tid < 128) {
            const int off = (12 * 256 + tid) * 16;
            __builtin_amdgcn_global_load_lds(
                (const __attribute__((address_space(1))) uint32_t*)(src + off),
                (__attribute__((address_space(3))) uint32_t*)(dst + off), 16, 0, 0);
        }
    }
    // --- stage B: 25600 B flat contiguous
    {
        const char* src = (const char*)(Wb + (size_t)o0 * LDK);
        char* dst = (char*)Bs;
#pragma unroll
        for (int it = 0; it < 6; it++) {
            const int off = (it * 256 + tid) * 16;
            __builtin_amdgcn_global_load_lds(
                (const __attribute__((address_space(1))) uint32_t*)(src + off),
                (__attribute__((address_space(3))) uint32_t*)(dst + off), 16, 0, 0);
        }
        if (tid < 64) {
            const int off = (6 * 256 + tid) * 16;
            __builtin_amdgcn_global_load_lds(
                (const __attribute__((address_space(1))) uint32_t*)(src + off),
                (__attribute__((address_space(3))) uint32_t*)(dst + off), 16, 0, 0);
        }
    }
    __syncthreads();

    // --- MFMA: 4 waves as 2(M) x 2(N); wave tile 64 x 32 = 4x2 of 16x16
    const int wave = tid >> 6;
    const int lane = tid & 63;
    const int wm   = (wave >> 1) * 64;
    const int wn   = (wave & 1) * 32;
    const int l15  = lane & 15;
    const int quad = lane >> 4;

    frag_cd acc[4][2];
#pragma unroll
    for (int i = 0; i < 4; i++)
#pragma unroll
        for (int j = 0; j < 2; j++)
            acc[i][j] = (frag_cd){0.f, 0.f, 0.f, 0.f};

#pragma unroll
    for (int kc = 0; kc < KPAD / 32; kc++) {
        const int kof = kc * 32 + quad * 8;
        frag_ab a[4], bfr[2];
#pragma unroll
        for (int mi = 0; mi < 4; mi++)
            a[mi] = *(const frag_ab*)&As[(wm + mi * 16 + l15) * LDK + kof];
#pragma unroll
        for (int ni = 0; ni < 2; ni++)
            bfr[ni] = *(const frag_ab*)&Bs[(wn + ni * 16 + l15) * LDK + kof];
#pragma unroll
        for (int mi = 0; mi < 4; mi++)
#pragma unroll
            for (int ni = 0; ni < 2; ni++)
                acc[mi][ni] = __builtin_amdgcn_mfma_f32_16x16x32_bf16(
                    a[mi], bfr[ni], acc[mi][ni], 0, 0, 0);
    }

    // --- epilogue: C/D layout col = lane&15 (n), row = quad*4 + reg (m)
    const size_t row0 = (size_t)mb * BM;
#pragma unroll
    for (int ni = 0; ni < 2; ni++) {
        const int o   = o0 + wn + ni * 16 + l15;
        const float bv = bias[o];
#pragma unroll
        for (int mi = 0; mi < 4; mi++) {
            const size_t rbase = row0 + wm + mi * 16 + quad * 4;
#pragma unroll
            for (int reg = 0; reg < 4; reg++) {
                out[(rbase + reg) * DMODEL + o] = acc[mi][ni][reg] + bv;
            }
        }
    }
}

// ---------------- fallback (round-1, known-correct, no ws) ----------------
#define FLDK 200
__global__ __launch_bounds__(256, 1)
void fused_tokenconv_kernel(const float* __restrict__ x,
                            const float* __restrict__ W,
                            const float* __restrict__ bias,
                            float* __restrict__ out)
{
    __shared__ __hip_bfloat16 As[128][FLDK];
    __shared__ __hip_bfloat16 Bs[128][FLDK];
    const int tid = threadIdx.x;
    const int blk = blockIdx.x;
    const int nb  = blk & 3;
    const int mb  = blk >> 2;
    const int b   = mb >> 4;
    const int t0  = (mb & 15) * 128;
    const int o0  = nb * 128;
    const float* xb = x + b * (SEQ * C_IN);

    for (int idx = tid; idx < 128 * KPAD; idx += 256) {
        int o_l = idx / KPAD;
        int i   = idx - o_l * KPAD;
        float v = (i < KDIM) ? W[(o0 + o_l) * KDIM + i] : 0.0f;
        Bs[o_l][i] = __float2bfloat16(v);
    }
    for (int idx = tid; idx < 128 * KPAD; idx += 256) {
        int t_l = idx / KPAD;
        int i   = idx - t_l * KPAD;
        float v = 0.0f;
        if (i < KDIM) {
            int c = i / 24;
            int r = i - c * 24;
            int m = r / 3;
            int h = r - m * 3;
            int s = (t0 + t_l + h - 1 + SEQ) & (SEQ - 1);
            if (s >= MTAPS * TAO) v = xb[(s - TAO * m) * C_IN + c];
        }
        As[t_l][i] = __float2bfloat16(v);
    }
    __syncthreads();

    const int wave = tid >> 6;
    const int lane = tid & 63;
    const int wm   = (wave >> 1) * 64;
    const int wn   = (wave & 1) * 64;
    const int l15  = lane & 15;
    const int quad = lane >> 4;

    frag_cd acc[4][4];
#pragma unroll
    for (int i = 0; i < 4; i++)
#pragma unroll
        for (int j = 0; j < 4; j++)
            acc[i][j] = (frag_cd){0.f, 0.f, 0.f, 0.f};

#pragma unroll
    for (int kc = 0; kc < KPAD / 32; kc++) {
        const int kof = kc * 32 + quad * 8;
        frag_ab a[4], bf[4];
#pragma unroll
        for (int mi = 0; mi < 4; mi++)
            a[mi] = *(const frag_ab*)&As[wm + mi * 16 + l15][kof];
#pragma unroll
        for (int ni = 0; ni < 4; ni++)
            bf[ni] = *(const frag_ab*)&Bs[wn + ni * 16 + l15][kof];
#pragma unroll
        for (int mi = 0; mi < 4; mi++)
#pragma unroll
            for (int ni = 0; ni < 4; ni++)
                acc[mi][ni] = __builtin_amdgcn_mfma_f32_16x16x32_bf16(
                    a[mi], bf[ni], acc[mi][ni], 0, 0, 0);
    }
    float* outb = out + (size_t)b * SEQ * DMODEL;
#pragma unroll
    for (int ni = 0; ni < 4; ni++) {
        const int o  = o0 + wn + ni * 16 + l15;
        const float bv = bias[o];
#pragma unroll
        for (int mi = 0; mi < 4; mi++) {
#pragma unroll
            for (int reg = 0; reg < 4; reg++) {
                const int t = t0 + wm + mi * 16 + quad * 4 + reg;
                outb[(size_t)t * DMODEL + o] = acc[mi][ni][reg] + bv;
            }
        }
    }
}

extern "C" void kernel_launch(void* const* d_in, const int* in_sizes, int n_in,
                              void* d_out, int out_size, void* d_ws, size_t ws_size,
                              hipStream_t stream) {
    const float* x    = (const float*)d_in[0];   // (32, 2048, 7) fp32
    const float* W    = (const float*)d_in[1];   // (512, 56, 3) fp32
    const float* bias = (const float*)d_in[2];   // (512,) fp32
    float* out        = (float*)d_out;           // (32, 2048, 512) fp32

    const size_t v_bytes = (size_t)NROWS * LDK * 2;          // 26,214,400
    const size_t w_bytes = (size_t)DMODEL * LDK * 2;         //    204,800
    if (ws_size >= v_bytes + w_bytes) {
        __hip_bfloat16* V  = (__hip_bfloat16*)d_ws;
        __hip_bfloat16* Wb = (__hip_bfloat16*)((char*)d_ws + v_bytes);
        hipLaunchKernelGGL(build_v_kernel, dim3(NROWS * 25 / 256), dim3(256), 0, stream, x, V);
        hipLaunchKernelGGL(build_w_kernel, dim3(DMODEL * 25 / 256), dim3(256), 0, stream, W, Wb);
        hipLaunchKernelGGL(gemm_kernel, dim3((NROWS / BM) * (DMODEL / BN)), dim3(256), 0, stream,
                           V, Wb, bias, out);
    } else {
        hipLaunchKernelGGL(fused_tokenconv_kernel, dim3(32 * 16 * 4), dim3(256), 0, stream,
                           x, W, bias, out);
    }
}

// Round 3
// 161.109 us; speedup vs baseline: 3.1759x; 1.1560x over previous
//
#include <hip/hip_runtime.h>
#include <hip/hip_bf16.h>
#include <stdint.h>

// out[b,t,o] = bias[o] + sum_{c<7,m<8,h<3} W[o, c*8+m, h] * Z[b, c*8+m, (t+h-1)&2047]
// Z[b, cm, s] = (s >= 168) ? x[b, s-24m, c] : 0
//
// Tap decomposition: out = sum_h G_shift(h-1) @ Wh[h]^T with
//   G[b*2048+t][c*8+m] = (t>=168) ? x[b, t-24m, c] : 0,  K=56 padded to 72 bf16
// (144 B row = 9x16B chunks; stride 144 B => 2-way LDS bank alias only, free).
// Row-(-1) wrap is exact: G row (t=0) is all zeros.

#define TAO    24
#define MTAPS  7
#define C_IN   7
#define SEQ    2048
#define DMODEL 512
#define KP     72      // padded K per tap (bf16), 144 B
#define RB     144     // row bytes
#define NROWS  65536   // 32*2048
#define BM     128
#define BN     128
#define AROWS  130     // BM + 2 halo rows
#define A_CHUNKS (AROWS * 9)          // 1170
#define B_CHUNKS (3 * BN * 9)         // 3456
#define BS_H_STRIDE (BN * RB)         // 18432 B per tap in LDS

typedef __attribute__((ext_vector_type(8))) short frag_ab;  // 8 bf16
typedef __attribute__((ext_vector_type(4))) float frag_cd;  // 4 fp32

// ---------------- phase 1a: build G (65536 x 72 bf16) ----------------
__global__ __launch_bounds__(256)
void build_g_kernel(const float* __restrict__ x, __hip_bfloat16* __restrict__ G)
{
    const int row = blockIdx.x * 256 + threadIdx.x;
    const int b   = row >> 11;
    const int t   = row & (SEQ - 1);
    const float* xb = x + b * (SEQ * C_IN);

    union { __hip_bfloat16 h[KP]; int4 v[9]; } u;
#pragma unroll
    for (int j = 0; j < 9; j++) u.v[j] = (int4){0, 0, 0, 0};

    if (t >= MTAPS * TAO) {
#pragma unroll
        for (int m = 0; m < 8; m++) {
            const float* p = xb + (t - TAO * m) * C_IN;
#pragma unroll
            for (int c = 0; c < C_IN; c++)
                u.h[c * 8 + m] = __float2bfloat16(p[c]);
        }
    }
    int4* dst = (int4*)((char*)G + (size_t)row * RB);
#pragma unroll
    for (int j = 0; j < 9; j++) dst[j] = u.v[j];
}

// ---------------- phase 1b: build Wh (3 x 512 x 72 bf16) ----------------
// Wb2[h][o][cm] = W[o*168 + cm*3 + h]
__global__ __launch_bounds__(256)
void build_w_kernel(const float* __restrict__ W, __hip_bfloat16* __restrict__ Wb2)
{
    const int idx = blockIdx.x * 256 + threadIdx.x;   // 1536 tasks
    const int h = idx / DMODEL;
    const int o = idx - h * DMODEL;

    union { __hip_bfloat16 s[KP]; int4 v[9]; } u;
#pragma unroll
    for (int j = 0; j < 9; j++) u.v[j] = (int4){0, 0, 0, 0};
#pragma unroll
    for (int cm = 0; cm < 56; cm++)
        u.s[cm] = __float2bfloat16(W[o * 168 + cm * 3 + h]);

    int4* dst = (int4*)((char*)Wb2 + (size_t)idx * RB);
#pragma unroll
    for (int j = 0; j < 9; j++) dst[j] = u.v[j];
}

// ---------------- phase 2: GEMM ----------------
__global__ __launch_bounds__(256, 2)
void gemm_kernel(const __hip_bfloat16* __restrict__ G,
                 const __hip_bfloat16* __restrict__ Wb2,
                 const float* __restrict__ bias,
                 float* __restrict__ out)
{
    __shared__ __align__(16) char lds[AROWS * RB + 3 * BN * RB];  // 18720 + 55296 = 74016 B
    char* As = lds;
    char* Bs = lds + AROWS * RB;

    const int tid = threadIdx.x;
    const int nb  = blockIdx.x & 3;      // 4 N-blocks
    const int mb  = blockIdx.x >> 2;     // 512 M-blocks
    const int b   = mb >> 4;
    const int t0  = (mb & 15) * BM;
    const int o0  = nb * BN;

    // --- stage A: 130 rows of G (halo +/-1), wrap via &2047 (row 0 is zeros)
    {
        const char* Gb = (const char*)G + (size_t)b * SEQ * RB;
        for (int q = tid; q < A_CHUNKS; q += 256) {
            const int row = q / 9;
            const int c16 = q - row * 9;
            const int srow = (t0 - 1 + row + SEQ) & (SEQ - 1);
            __builtin_amdgcn_global_load_lds(
                (const __attribute__((address_space(1))) uint32_t*)(Gb + (size_t)srow * RB + c16 * 16),
                (__attribute__((address_space(3))) uint32_t*)(As + q * 16), 16, 0, 0);
        }
    }
    // --- stage B: 3 taps x 128 rows of Wb2
    {
        for (int q = tid; q < B_CHUNKS; q += 256) {
            const int h = q / (BN * 9);
            const int rem = q - h * (BN * 9);
            const char* src = (const char*)Wb2 + ((size_t)(h * DMODEL + o0)) * RB + rem * 16;
            __builtin_amdgcn_global_load_lds(
                (const __attribute__((address_space(1))) uint32_t*)src,
                (__attribute__((address_space(3))) uint32_t*)(Bs + q * 16), 16, 0, 0);
        }
    }
    __syncthreads();

    // --- MFMA: 4 waves as 2(M) x 2(N); wave tile 64x64 = 4x4 of 16x16
    const int wave = tid >> 6;
    const int lane = tid & 63;
    const int wm   = (wave >> 1) * 64;
    const int wn   = (wave & 1) * 64;
    const int l15  = lane & 15;
    const int quad = lane >> 4;

    frag_cd acc[4][4];
#pragma unroll
    for (int i = 0; i < 4; i++)
#pragma unroll
        for (int j = 0; j < 4; j++)
            acc[i][j] = (frag_cd){0.f, 0.f, 0.f, 0.f};

#pragma unroll
    for (int h = 0; h < 3; h++) {
#pragma unroll
        for (int kc = 0; kc < 2; kc++) {
            const int kbyte = kc * 64 + quad * 16;
            frag_ab a[4], bf[4];
#pragma unroll
            for (int mi = 0; mi < 4; mi++)
                a[mi] = *(const frag_ab*)(As + (wm + mi * 16 + l15 + h) * RB + kbyte);
#pragma unroll
            for (int ni = 0; ni < 4; ni++)
                bf[ni] = *(const frag_ab*)(Bs + h * BS_H_STRIDE + (wn + ni * 16 + l15) * RB + kbyte);
#pragma unroll
            for (int mi = 0; mi < 4; mi++)
#pragma unroll
                for (int ni = 0; ni < 4; ni++)
                    acc[mi][ni] = __builtin_amdgcn_mfma_f32_16x16x32_bf16(
                        a[mi], bf[ni], acc[mi][ni], 0, 0, 0);
        }
    }

    // --- epilogue: C/D layout col = lane&15 (n=o), row = quad*4 + reg (m=t)
    const size_t row0 = (size_t)mb * BM;
#pragma unroll
    for (int ni = 0; ni < 4; ni++) {
        const int o   = o0 + wn + ni * 16 + l15;
        const float bv = bias[o];
#pragma unroll
        for (int mi = 0; mi < 4; mi++) {
            const size_t rbase = row0 + wm + mi * 16 + quad * 4;
#pragma unroll
            for (int reg = 0; reg < 4; reg++) {
                out[(rbase + reg) * DMODEL + o] = acc[mi][ni][reg] + bv;
            }
        }
    }
}

// ---------------- fallback (round-1, known-correct, no ws) ----------------
#define KDIM  168
#define KPAD  192
#define FLDK  200
__global__ __launch_bounds__(256, 1)
void fused_tokenconv_kernel(const float* __restrict__ x,
                            const float* __restrict__ W,
                            const float* __restrict__ bias,
                            float* __restrict__ out)
{
    __shared__ __hip_bfloat16 As[128][FLDK];
    __shared__ __hip_bfloat16 Bs[128][FLDK];
    const int tid = threadIdx.x;
    const int blk = blockIdx.x;
    const int nb  = blk & 3;
    const int mb  = blk >> 2;
    const int b   = mb >> 4;
    const int t0  = (mb & 15) * 128;
    const int o0  = nb * 128;
    const float* xb = x + b * (SEQ * C_IN);

    for (int idx = tid; idx < 128 * KPAD; idx += 256) {
        int o_l = idx / KPAD;
        int i   = idx - o_l * KPAD;
        float v = (i < KDIM) ? W[(o0 + o_l) * KDIM + i] : 0.0f;
        Bs[o_l][i] = __float2bfloat16(v);
    }
    for (int idx = tid; idx < 128 * KPAD; idx += 256) {
        int t_l = idx / KPAD;
        int i   = idx - t_l * KPAD;
        float v = 0.0f;
        if (i < KDIM) {
            int c = i / 24;
            int r = i - c * 24;
            int m = r / 3;
            int h = r - m * 3;
            int s = (t0 + t_l + h - 1 + SEQ) & (SEQ - 1);
            if (s >= MTAPS * TAO) v = xb[(s - TAO * m) * C_IN + c];
        }
        As[t_l][i] = __float2bfloat16(v);
    }
    __syncthreads();

    const int wave = tid >> 6;
    const int lane = tid & 63;
    const int wm   = (wave >> 1) * 64;
    const int wn   = (wave & 1) * 64;
    const int l15  = lane & 15;
    const int quad = lane >> 4;

    frag_cd acc[4][4];
#pragma unroll
    for (int i = 0; i < 4; i++)
#pragma unroll
        for (int j = 0; j < 4; j++)
            acc[i][j] = (frag_cd){0.f, 0.f, 0.f, 0.f};

#pragma unroll
    for (int kc = 0; kc < KPAD / 32; kc++) {
        const int kof = kc * 32 + quad * 8;
        frag_ab a[4], bf[4];
#pragma unroll
        for (int mi = 0; mi < 4; mi++)
            a[mi] = *(const frag_ab*)&As[wm + mi * 16 + l15][kof];
#pragma unroll
        for (int ni = 0; ni < 4; ni++)
            bf[ni] = *(const frag_ab*)&Bs[wn + ni * 16 + l15][kof];
#pragma unroll
        for (int mi = 0; mi < 4; mi++)
#pragma unroll
            for (int ni = 0; ni < 4; ni++)
                acc[mi][ni] = __builtin_amdgcn_mfma_f32_16x16x32_bf16(
                    a[mi], bf[ni], acc[mi][ni], 0, 0, 0);
    }
    float* outb = out + (size_t)b * SEQ * DMODEL;
#pragma unroll
    for (int ni = 0; ni < 4; ni++) {
        const int o  = o0 + wn + ni * 16 + l15;
        const float bv = bias[o];
#pragma unroll
        for (int mi = 0; mi < 4; mi++) {
#pragma unroll
            for (int reg = 0; reg < 4; reg++) {
                const int t = t0 + wm + mi * 16 + quad * 4 + reg;
                outb[(size_t)t * DMODEL + o] = acc[mi][ni][reg] + bv;
            }
        }
    }
}

extern "C" void kernel_launch(void* const* d_in, const int* in_sizes, int n_in,
                              void* d_out, int out_size, void* d_ws, size_t ws_size,
                              hipStream_t stream) {
    const float* x    = (const float*)d_in[0];   // (32, 2048, 7) fp32
    const float* W    = (const float*)d_in[1];   // (512, 56, 3) fp32
    const float* bias = (const float*)d_in[2];   // (512,) fp32
    float* out        = (float*)d_out;           // (32, 2048, 512) fp32

    const size_t g_bytes = (size_t)NROWS * RB;          // 9,437,184
    const size_t w_bytes = (size_t)3 * DMODEL * RB;     //   221,184
    if (ws_size >= g_bytes + w_bytes) {
        __hip_bfloat16* G   = (__hip_bfloat16*)d_ws;
        __hip_bfloat16* Wb2 = (__hip_bfloat16*)((char*)d_ws + g_bytes);
        hipLaunchKernelGGL(build_g_kernel, dim3(NROWS / 256), dim3(256), 0, stream, x, G);
        hipLaunchKernelGGL(build_w_kernel, dim3(3 * DMODEL / 256), dim3(256), 0, stream, W, Wb2);
        hipLaunchKernelGGL(gemm_kernel, dim3((NROWS / BM) * (DMODEL / BN)), dim3(256), 0, stream,
                           G, Wb2, bias, out);
    } else {
        hipLaunchKernelGGL(fused_tokenconv_kernel, dim3(32 * 16 * 4), dim3(256), 0, stream,
                           x, W, bias, out);
    }
}